// Round 1
// baseline (229.990 us; speedup 1.0000x reference)
//
#include <hip/hip_runtime.h>

#define NQ 9
#define NS 512            // 2^9 amplitudes
#define M2 1024           // [Re V; Im V] stacked rows

typedef __attribute__((ext_vector_type(8))) short bf16x8;
typedef __attribute__((ext_vector_type(4))) float f32x4;

__device__ inline float2 cmul(float2 a, float2 b){
  return make_float2(a.x*b.x - a.y*b.y, a.x*b.y + a.y*b.x);
}

__device__ inline unsigned short f2bf(float f){
  unsigned int u = __float_as_uint(f);
  u += 0x7fffu + ((u >> 16) & 1u);   // round-to-nearest-even
  return (unsigned short)(u >> 16);
}

// ---------------- gates on an LDS state vector (one V column per block) ----------------
// wire w <-> bit (8-w) of the flat index (wire 0 is MSB, row-major flatten)

__device__ inline void apply1q(float2* st, int tid, int w,
                               float2 u00, float2 u01, float2 u10, float2 u11){
  __syncthreads();
  int b = 8 - w, m = 1 << b;
  int i0 = ((tid & ~(m - 1)) << 1) | (tid & (m - 1));
  int i1 = i0 | m;
  float2 a0 = st[i0], a1 = st[i1];
  float2 r0 = cmul(u00, a0), t0 = cmul(u01, a1);
  float2 r1 = cmul(u10, a0), t1 = cmul(u11, a1);
  st[i0] = make_float2(r0.x + t0.x, r0.y + t0.y);
  st[i1] = make_float2(r1.x + t1.x, r1.y + t1.y);
}

__device__ inline void apply_ry(float2* st, int tid, int w, float c, float s){
  __syncthreads();
  int b = 8 - w, m = 1 << b;
  int i0 = ((tid & ~(m - 1)) << 1) | (tid & (m - 1));
  int i1 = i0 | m;
  float2 a0 = st[i0], a1 = st[i1];
  st[i0] = make_float2(c*a0.x - s*a1.x, c*a0.y - s*a1.y);
  st[i1] = make_float2(s*a0.x + c*a1.x, s*a0.y + c*a1.y);
}

__device__ inline void apply_x(float2* st, int tid, int w){
  __syncthreads();
  int b = 8 - w, m = 1 << b;
  int i0 = ((tid & ~(m - 1)) << 1) | (tid & (m - 1));
  int i1 = i0 | m;
  float2 a0 = st[i0], a1 = st[i1];
  st[i0] = a1; st[i1] = a0;
}

__device__ inline void idx2q(int tid, int bc, int bt, int& i0, int& i1){
  int b1 = bc < bt ? bc : bt;
  int b2 = bc < bt ? bt : bc;
  int x = tid;
  x = ((x >> b1) << (b1 + 1)) | (x & ((1 << b1) - 1));   // insert 0 at b1
  x = ((x >> b2) << (b2 + 1)) | (x & ((1 << b2) - 1));   // insert 0 at b2
  i0 = x | (1 << bc);        // control = 1, target = 0
  i1 = i0 | (1 << bt);       // control = 1, target = 1
}

__device__ inline void apply_cnot(float2* st, int tid, int wc, int wt){
  __syncthreads();
  if (tid < 128){
    int i0, i1; idx2q(tid, 8 - wc, 8 - wt, i0, i1);
    float2 a0 = st[i0], a1 = st[i1];
    st[i0] = a1; st[i1] = a0;
  }
}

// CRZ(t): ctrl=1 -> diag(e^{-it/2}, e^{+it/2}); c=cos(t/2), s=sin(t/2)
__device__ inline void apply_crz(float2* st, int tid, int wc, int wt, float c, float s){
  __syncthreads();
  if (tid < 128){
    int i0, i1; idx2q(tid, 8 - wc, 8 - wt, i0, i1);
    float2 a0 = st[i0], a1 = st[i1];
    st[i0] = make_float2(c*a0.x + s*a0.y, c*a0.y - s*a0.x);   // * (c - i s)
    st[i1] = make_float2(c*a1.x - s*a1.y, c*a1.y + s*a1.x);   // * (c + i s)
  }
}

// CRX(t): ctrl=1 -> [[c, -is],[-is, c]]
__device__ inline void apply_crx(float2* st, int tid, int wc, int wt, float c, float s){
  __syncthreads();
  if (tid < 128){
    int i0, i1; idx2q(tid, 8 - wc, 8 - wt, i0, i1);
    float2 a0 = st[i0], a1 = st[i1];
    st[i0] = make_float2(c*a0.x + s*a1.y, c*a0.y - s*a1.x);
    st[i1] = make_float2(s*a0.y + c*a1.x, -s*a0.x + c*a1.y);
  }
}

__device__ void entangle_block(float2* st, int tid, const float* __restrict__ p){
  for (int i = 0; i < NQ; ++i){
    int ip = (i + 1) % NQ;
    float s, c;
    __sincosf(0.5f * p[4*i + 0], &s, &c);
    apply_ry(st, tid, i, c, s);
    __sincosf(0.5f * p[4*i + 1], &s, &c);
    apply_ry(st, tid, ip, c, s);
    apply_cnot(st, tid, i, ip);
    __sincosf(0.5f * p[4*i + 2], &s, &c);
    apply_crz(st, tid, i, ip, c, s);
    apply_x(st, tid, ip);
    __sincosf(0.5f * p[4*i + 3], &s, &c);
    apply_crx(st, tid, i, ip, c, s);
  }
}

__device__ void sel_layer_dev(float2* st, int tid, const float* __restrict__ w, int r){
  for (int i = 0; i < NQ; ++i){
    float phi = w[3*i], th = w[3*i + 1], om = w[3*i + 2];
    float sT, cT_, sA, cA, sB, cB;
    __sincosf(0.5f * th, &sT, &cT_);
    __sincosf(0.5f * (phi + om), &sA, &cA);
    __sincosf(0.5f * (om - phi), &sB, &cB);
    // Rot = RZ(om) RY(th) RZ(phi)
    float2 u00 = make_float2( cA*cT_, -sA*cT_);
    float2 u01 = make_float2(-cB*sT,   sB*sT );
    float2 u10 = make_float2( cB*sT,   sB*sT );
    float2 u11 = make_float2( cA*cT_,  sA*cT_);
    apply1q(st, tid, i, u00, u01, u10, u11);
  }
  for (int i = 0; i < NQ; ++i)
    apply_cnot(st, tid, i, (i + r) % NQ);
}

// One block per column t: evolve (-i)^pc(t) * e_t through the fixed circuit.
// Write A2[row][t] bf16, rows 0..511 = Re, 512..1023 = Im.
__global__ __launch_bounds__(256) void sim_V(const float* __restrict__ params,
                                             const float* __restrict__ weights,
                                             const float* __restrict__ params2,
                                             unsigned short* __restrict__ A2){
  __shared__ float2 st[NS];
  int t = blockIdx.x;
  int tid = threadIdx.x;
  st[tid] = make_float2(0.f, 0.f);
  st[tid + 256] = make_float2(0.f, 0.f);
  __syncthreads();
  if (tid == 0){
    int pc = __popc(t) & 3;
    float2 v = (pc == 0) ? make_float2( 1.f,  0.f) :
               (pc == 1) ? make_float2( 0.f, -1.f) :
               (pc == 2) ? make_float2(-1.f,  0.f) : make_float2(0.f, 1.f);
    st[t] = v;
  }
  for (int l = 0; l < 3; ++l) entangle_block(st, tid, params + l*36);
  for (int l = 0; l < 3; ++l) sel_layer_dev(st, tid, weights + l*27, l + 1);
  for (int l = 0; l < 5; ++l) entangle_block(st, tid, params2 + l*36);
  __syncthreads();
  for (int s = tid; s < NS; s += 256){
    float2 v = st[s];
    A2[(size_t)s * NS + t]        = f2bf(v.x);
    A2[(size_t)(s + NS) * NS + t] = f2bf(v.y);
  }
}

// cT[b][t] = prod_w (bit(8-w) of t ? sin(adds[b,w]/2) : cos(adds[b,w]/2))   (real, bf16)
__global__ __launch_bounds__(256) void build_c(const float* __restrict__ adds,
                                               unsigned short* __restrict__ cT, int B){
  int b = blockIdx.x * 256 + threadIdx.x;
  if (b >= B) return;
  float cw[NQ], sw[NQ];
  #pragma unroll
  for (int w = 0; w < NQ; ++w)
    __sincosf(0.5f * adds[b*NQ + w], &sw[w], &cw[w]);
  unsigned short* row = cT + (size_t)b * NS;
  for (int hi = 0; hi < 64; ++hi){           // wires 0..5 (bits 8..3)
    float p6 = ((hi>>5)&1 ? sw[0] : cw[0]) * ((hi>>4)&1 ? sw[1] : cw[1])
             * ((hi>>3)&1 ? sw[2] : cw[2]) * ((hi>>2)&1 ? sw[3] : cw[3])
             * ((hi>>1)&1 ? sw[4] : cw[4]) * ( hi     &1 ? sw[5] : cw[5]);
    #pragma unroll
    for (int lo = 0; lo < 8; ++lo){          // wires 6..8 (bits 2..0)
      float p = p6 * ((lo>>2)&1 ? sw[6] : cw[6])
                   * ((lo>>1)&1 ? sw[7] : cw[7])
                   * ( lo     &1 ? sw[8] : cw[8]);
      row[hi*8 + lo] = f2bf(p);
    }
  }
}

// Phi2 = A2(1024x512) @ c(512xB); out[b] = sum_row sign(row) * Phi2[row][b]^2,
// sign(row) = -1 iff (row & 256). Fused: per 128x128 tile compute column sums of
// sign*phi^2 and atomicAdd into out.
__global__ __launch_bounds__(256) void gemm_out(const unsigned short* __restrict__ A2,
                                                const unsigned short* __restrict__ cT,
                                                float* __restrict__ out){
  int bx = blockIdx.x;            // N tile (128 cols of b)
  int by = blockIdx.y;            // M tile (128 rows), 8 tiles
  int tid = threadIdx.x;
  int wave = tid >> 6, lane = tid & 63;
  int wy = wave >> 1, wx = wave & 1;
  int lane15 = lane & 15, quad = lane >> 4;
  int rowBase = by*128 + wy*64;
  int colBase = bx*128 + wx*64;
  const short* Ap = (const short*)A2;   // [row][k], k-stride 1, row-stride 512
  const short* Bp = (const short*)cT;   // [col][k]

  f32x4 acc[4][4];
  #pragma unroll
  for (int i = 0; i < 4; ++i)
    #pragma unroll
    for (int j = 0; j < 4; ++j)
      acc[i][j] = (f32x4){0.f, 0.f, 0.f, 0.f};

  #pragma unroll 2
  for (int k0 = 0; k0 < NS; k0 += 32){
    bf16x8 a[4], b[4];
    #pragma unroll
    for (int mi = 0; mi < 4; ++mi)
      a[mi] = *(const bf16x8*)(Ap + (size_t)(rowBase + mi*16 + lane15)*NS + k0 + quad*8);
    #pragma unroll
    for (int ni = 0; ni < 4; ++ni)
      b[ni] = *(const bf16x8*)(Bp + (size_t)(colBase + ni*16 + lane15)*NS + k0 + quad*8);
    #pragma unroll
    for (int mi = 0; mi < 4; ++mi)
      #pragma unroll
      for (int ni = 0; ni < 4; ++ni)
        acc[mi][ni] = __builtin_amdgcn_mfma_f32_16x16x32_bf16(a[mi], b[ni], acc[mi][ni], 0, 0, 0);
  }

  float sign = (by & 2) ? -1.f : 1.f;   // rows of this tile share (row & 256)
  #pragma unroll
  for (int ni = 0; ni < 4; ++ni){
    float cs = 0.f;
    #pragma unroll
    for (int mi = 0; mi < 4; ++mi)
      #pragma unroll
      for (int r = 0; r < 4; ++r)
        cs += acc[mi][ni][r] * acc[mi][ni][r];
    cs += __shfl_xor(cs, 16);
    cs += __shfl_xor(cs, 32);
    if (quad == 0)
      atomicAdd(out + colBase + ni*16 + lane15, sign * cs);
  }
}

extern "C" void kernel_launch(void* const* d_in, const int* in_sizes, int n_in,
                              void* d_out, int out_size, void* d_ws, size_t ws_size,
                              hipStream_t stream) {
  const float* adds    = (const float*)d_in[0];
  const float* params  = (const float*)d_in[1];
  const float* weights = (const float*)d_in[2];
  const float* params2 = (const float*)d_in[3];
  float* out = (float*)d_out;
  int B = in_sizes[0] / NQ;   // 8192

  unsigned short* A2 = (unsigned short*)d_ws;        // 1024*512 bf16 = 1 MB
  unsigned short* cT = A2 + (size_t)M2 * NS;         // B*512 bf16 = 8 MB

  hipMemsetAsync(d_out, 0, (size_t)B * sizeof(float), stream);
  hipLaunchKernelGGL(sim_V, dim3(NS), dim3(256), 0, stream, params, weights, params2, A2);
  hipLaunchKernelGGL(build_c, dim3((B + 255) / 256), dim3(256), 0, stream, adds, cT, B);
  hipLaunchKernelGGL(gemm_out, dim3(B / 128, 8), dim3(256), 0, stream, A2, cT, out);
}

// Round 2
// 174.308 us; speedup vs baseline: 1.3194x; 1.3194x over previous
//
#include <hip/hip_runtime.h>

#define NQ 9
#define NS 512            // 2^9 amplitudes
#define M2 1024           // [Re V; Im V] stacked rows

typedef __attribute__((ext_vector_type(8))) short bf16x8;
typedef __attribute__((ext_vector_type(4))) float f32x4;

__device__ inline unsigned short f2bf(float f){
  unsigned int u = __float_as_uint(f);
  u += 0x7fffu + ((u >> 16) & 1u);   // round-to-nearest-even
  return (unsigned short)(u >> 16);
}

// =====================  register-resident statevector sim  =====================
// One wave per column t. Lane L holds amplitudes idx = L*8 + j (j=0..7).
// State bit b: b>=3 -> lane bit (b-3), b<3 -> register index bit.
// Wire w <-> bit (8-w)  (wire 0 = MSB of flat index).

template<int B>
__device__ inline void g_ry(float* ax, float* ay, int lane, float c, float s){
  if constexpr (B < 3){
    constexpr int m = 1 << B;
    #pragma unroll
    for (int j0 = 0; j0 < 8; ++j0) if ((j0 & m) == 0){
      int j1 = j0 | m;
      float x0 = ax[j0], x1 = ax[j1];
      ax[j0] = c*x0 - s*x1;  ax[j1] = s*x0 + c*x1;
      float y0 = ay[j0], y1 = ay[j1];
      ay[j0] = c*y0 - s*y1;  ay[j1] = s*y0 + c*y1;
    }
  } else {
    constexpr int lm = 1 << (B - 3);
    float se = (lane & lm) ? s : -s;
    #pragma unroll
    for (int j = 0; j < 8; ++j){
      float px = __shfl_xor(ax[j], lm);
      float py = __shfl_xor(ay[j], lm);
      ax[j] = c*ax[j] + se*px;
      ay[j] = c*ay[j] + se*py;
    }
  }
}

template<int B>
__device__ inline void g_rot(float* ax, float* ay, int lane,
                             float u00x,float u00y,float u01x,float u01y,
                             float u10x,float u10y,float u11x,float u11y){
  if constexpr (B < 3){
    constexpr int m = 1 << B;
    #pragma unroll
    for (int j0 = 0; j0 < 8; ++j0) if ((j0 & m) == 0){
      int j1 = j0 | m;
      float x0=ax[j0], y0=ay[j0], x1=ax[j1], y1=ay[j1];
      ax[j0] = u00x*x0 - u00y*y0 + u01x*x1 - u01y*y1;
      ay[j0] = u00x*y0 + u00y*x0 + u01x*y1 + u01y*x1;
      ax[j1] = u10x*x0 - u10y*y0 + u11x*x1 - u11y*y1;
      ay[j1] = u10x*y0 + u10y*x0 + u11x*y1 + u11y*x1;
    }
  } else {
    constexpr int lm = 1 << (B - 3);
    bool hi = (lane & lm) != 0;
    float cax = hi ? u11x : u00x, cay = hi ? u11y : u00y;
    float cbx = hi ? u10x : u01x, cby = hi ? u10y : u01y;
    #pragma unroll
    for (int j = 0; j < 8; ++j){
      float px = __shfl_xor(ax[j], lm), py = __shfl_xor(ay[j], lm);
      float ox = ax[j], oy = ay[j];
      ax[j] = cax*ox - cay*oy + cbx*px - cby*py;
      ay[j] = cax*oy + cay*ox + cbx*py + cby*px;
    }
  }
}

// CNOT(c,t) followed by CRZ(c,t):  ctrl=1: new a_t0 = (c - i s) * old a_t1,
//                                          new a_t1 = (c + i s) * old a_t0
template<int BC, int BT>
__device__ inline void g_cnot_crz(float* ax, float* ay, int lane, float c, float s){
  if constexpr (BC < 3 && BT < 3){
    constexpr int mc = 1<<BC, mt = 1<<BT;
    #pragma unroll
    for (int j = 0; j < 8; ++j) if ((j & mc) && !(j & mt)){
      int j1 = j | mt;
      float x0=ax[j], y0=ay[j], x1=ax[j1], y1=ay[j1];
      ax[j]  = c*x1 + s*y1;  ay[j]  = c*y1 - s*x1;
      ax[j1] = c*x0 - s*y0;  ay[j1] = c*y0 + s*x0;
    }
  } else if constexpr (BC < 3){            // ctrl reg, target lane
    constexpr int mc = 1<<BC, lmt = 1<<(BT-3);
    float se = (lane & lmt) ? -s : s;
    #pragma unroll
    for (int j = 0; j < 8; ++j) if (j & mc){
      float px = __shfl_xor(ax[j], lmt), py = __shfl_xor(ay[j], lmt);
      ax[j] = c*px + se*py;
      ay[j] = c*py - se*px;
    }
  } else if constexpr (BT < 3){            // ctrl lane, target reg
    constexpr int lmc = 1<<(BC-3), mt = 1<<BT;
    bool ct = (lane & lmc) != 0;
    #pragma unroll
    for (int j = 0; j < 8; ++j) if (!(j & mt)){
      int j1 = j | mt;
      float x0=ax[j], y0=ay[j], x1=ax[j1], y1=ay[j1];
      float nx0 = c*x1 + s*y1, ny0 = c*y1 - s*x1;
      float nx1 = c*x0 - s*y0, ny1 = c*y0 + s*x0;
      ax[j]  = ct ? nx0 : x0;  ay[j]  = ct ? ny0 : y0;
      ax[j1] = ct ? nx1 : x1;  ay[j1] = ct ? ny1 : y1;
    }
  } else {                                  // both lane
    constexpr int lmc = 1<<(BC-3), lmt = 1<<(BT-3);
    bool ct = (lane & lmc) != 0;
    float se = (lane & lmt) ? -s : s;
    #pragma unroll
    for (int j = 0; j < 8; ++j){
      float px = __shfl_xor(ax[j], lmt), py = __shfl_xor(ay[j], lmt);
      float nx = c*px + se*py, ny = c*py - se*px;
      ax[j] = ct ? nx : ax[j];
      ay[j] = ct ? ny : ay[j];
    }
  }
}

// X(t) followed by CRX(c,t): ctrl=0: swap target pair;
// ctrl=1: new a_t0 = -i s a_t0 + c a_t1 ; new a_t1 = c a_t0 - i s a_t1
template<int BC, int BT>
__device__ inline void g_x_crx(float* ax, float* ay, int lane, float c, float s){
  if constexpr (BC < 3 && BT < 3){
    constexpr int mc = 1<<BC, mt = 1<<BT;
    #pragma unroll
    for (int j = 0; j < 8; ++j) if (!(j & mt)){
      int j1 = j | mt;
      float x0=ax[j], y0=ay[j], x1=ax[j1], y1=ay[j1];
      if (j & mc){
        ax[j]  = c*x1 + s*y0;  ay[j]  = c*y1 - s*x0;
        ax[j1] = c*x0 + s*y1;  ay[j1] = c*y0 - s*x1;
      } else {
        ax[j] = x1; ay[j] = y1; ax[j1] = x0; ay[j1] = y0;
      }
    }
  } else if constexpr (BC < 3){            // ctrl reg, target lane
    constexpr int mc = 1<<BC, lmt = 1<<(BT-3);
    #pragma unroll
    for (int j = 0; j < 8; ++j){
      float px = __shfl_xor(ax[j], lmt), py = __shfl_xor(ay[j], lmt);
      if (j & mc){
        float ox = ax[j], oy = ay[j];
        ax[j] = c*px + s*oy;
        ay[j] = c*py - s*ox;
      } else { ax[j] = px; ay[j] = py; }
    }
  } else if constexpr (BT < 3){            // ctrl lane, target reg
    constexpr int lmc = 1<<(BC-3), mt = 1<<BT;
    bool ct = (lane & lmc) != 0;
    float ce = ct ? c : 1.f, sg = ct ? s : 0.f;
    #pragma unroll
    for (int j = 0; j < 8; ++j) if (!(j & mt)){
      int j1 = j | mt;
      float x0=ax[j], y0=ay[j], x1=ax[j1], y1=ay[j1];
      ax[j]  = ce*x1 + sg*y0;  ay[j]  = ce*y1 - sg*x0;
      ax[j1] = ce*x0 + sg*y1;  ay[j1] = ce*y0 - sg*x1;
    }
  } else {                                  // both lane
    constexpr int lmc = 1<<(BC-3), lmt = 1<<(BT-3);
    bool ct = (lane & lmc) != 0;
    float ce = ct ? c : 1.f, sg = ct ? s : 0.f;
    #pragma unroll
    for (int j = 0; j < 8; ++j){
      float px = __shfl_xor(ax[j], lmt), py = __shfl_xor(ay[j], lmt);
      float ox = ax[j], oy = ay[j];
      ax[j] = ce*px + sg*oy;
      ay[j] = ce*py - sg*ox;
    }
  }
}

template<int BC, int BT>
__device__ inline void g_cnot(float* ax, float* ay, int lane){
  if constexpr (BC < 3 && BT < 3){
    constexpr int mc = 1<<BC, mt = 1<<BT;
    #pragma unroll
    for (int j = 0; j < 8; ++j) if ((j & mc) && !(j & mt)){
      int j1 = j | mt;
      float x0=ax[j], y0=ay[j];
      ax[j]=ax[j1]; ay[j]=ay[j1]; ax[j1]=x0; ay[j1]=y0;
    }
  } else if constexpr (BC < 3){
    constexpr int mc = 1<<BC, lmt = 1<<(BT-3);
    #pragma unroll
    for (int j = 0; j < 8; ++j) if (j & mc){
      ax[j] = __shfl_xor(ax[j], lmt);
      ay[j] = __shfl_xor(ay[j], lmt);
    }
  } else if constexpr (BT < 3){
    constexpr int lmc = 1<<(BC-3), mt = 1<<BT;
    bool ct = (lane & lmc) != 0;
    #pragma unroll
    for (int j = 0; j < 8; ++j) if (!(j & mt)){
      int j1 = j | mt;
      float x0=ax[j], y0=ay[j], x1=ax[j1], y1=ay[j1];
      ax[j]  = ct ? x1 : x0;  ay[j]  = ct ? y1 : y0;
      ax[j1] = ct ? x0 : x1;  ay[j1] = ct ? y0 : y1;
    }
  } else {
    constexpr int lmc = 1<<(BC-3), lmt = 1<<(BT-3);
    bool ct = (lane & lmc) != 0;
    #pragma unroll
    for (int j = 0; j < 8; ++j){
      float px = __shfl_xor(ax[j], lmt), py = __shfl_xor(ay[j], lmt);
      ax[j] = ct ? px : ax[j];
      ay[j] = ct ? py : ay[j];
    }
  }
}

// ---------------- circuit drivers (compile-time unrolled) ----------------

template<int I>
__device__ inline void ent_step(float* ax, float* ay, int lane, const float* __restrict__ p){
  constexpr int IP = (I + 1) % 9;
  float s0,c0,s1,c1,s2,c2,s3,c3;
  __sincosf(0.5f*p[4*I+0], &s0, &c0);
  __sincosf(0.5f*p[4*I+1], &s1, &c1);
  __sincosf(0.5f*p[4*I+2], &s2, &c2);
  __sincosf(0.5f*p[4*I+3], &s3, &c3);
  g_ry<8-I >(ax, ay, lane, c0, s0);
  g_ry<8-IP>(ax, ay, lane, c1, s1);
  g_cnot_crz<8-I, 8-IP>(ax, ay, lane, c2, s2);
  g_x_crx  <8-I, 8-IP>(ax, ay, lane, c3, s3);
}

template<int I = 0>
__device__ inline void ent_block(float* ax, float* ay, int lane, const float* __restrict__ p){
  ent_step<I>(ax, ay, lane, p);
  if constexpr (I < 8) ent_block<I+1>(ax, ay, lane, p);
}

template<int I>
__device__ inline void rot_one(float* ax, float* ay, int lane, const float* __restrict__ w){
  float phi = w[3*I], th = w[3*I+1], om = w[3*I+2];
  float sT,cT,sA,cA,sB,cB;
  __sincosf(0.5f*th, &sT, &cT);
  __sincosf(0.5f*(phi+om), &sA, &cA);
  __sincosf(0.5f*(om-phi), &sB, &cB);
  g_rot<8-I>(ax, ay, lane,
             cA*cT, -sA*cT,    // u00
            -cB*sT,  sB*sT,    // u01
             cB*sT,  sB*sT,    // u10
             cA*cT,  sA*cT);   // u11
}

template<int I = 0>
__device__ inline void sel_rots(float* ax, float* ay, int lane, const float* __restrict__ w){
  rot_one<I>(ax, ay, lane, w);
  if constexpr (I < 8) sel_rots<I+1>(ax, ay, lane, w);
}

template<int R, int I = 0>
__device__ inline void sel_cnots(float* ax, float* ay, int lane){
  g_cnot<8-I, 8-((I+R)%9)>(ax, ay, lane);
  if constexpr (I < 8) sel_cnots<R, I+1>(ax, ay, lane);
}

template<int R>
__device__ inline void sel_layer(float* ax, float* ay, int lane, const float* __restrict__ w){
  sel_rots<0>(ax, ay, lane, w);
  sel_cnots<R, 0>(ax, ay, lane);
}

// One wave per column t. Writes A2T[t][0..511]=Re, A2T[t][512..1023]=Im (bf16),
// fully coalesced (16B per lane).
__global__ __launch_bounds__(64) void sim_V(const float* __restrict__ params,
                                            const float* __restrict__ weights,
                                            const float* __restrict__ params2,
                                            unsigned short* __restrict__ A2T){
  int lane = threadIdx.x;
  int t = blockIdx.x;
  float ax[8], ay[8];
  int pc = __popc((unsigned)t) & 3;
  float prx = (pc==0) ? 1.f : (pc==2 ? -1.f : 0.f);
  float pry = (pc==3) ? 1.f : (pc==1 ? -1.f : 0.f);
  int hl = t >> 3, lj = t & 7;
  #pragma unroll
  for (int j = 0; j < 8; ++j){
    bool hit = (lane == hl) && (j == lj);
    ax[j] = hit ? prx : 0.f;
    ay[j] = hit ? pry : 0.f;
  }
  ent_block<0>(ax, ay, lane, params);
  ent_block<0>(ax, ay, lane, params + 36);
  ent_block<0>(ax, ay, lane, params + 72);
  sel_layer<1>(ax, ay, lane, weights);
  sel_layer<2>(ax, ay, lane, weights + 27);
  sel_layer<3>(ax, ay, lane, weights + 54);
  ent_block<0>(ax, ay, lane, params2);
  ent_block<0>(ax, ay, lane, params2 + 36);
  ent_block<0>(ax, ay, lane, params2 + 72);
  ent_block<0>(ax, ay, lane, params2 + 108);
  ent_block<0>(ax, ay, lane, params2 + 144);

  union { unsigned short u[8]; uint4 v; } re, im;
  #pragma unroll
  for (int j = 0; j < 8; ++j){ re.u[j] = f2bf(ax[j]); im.u[j] = f2bf(ay[j]); }
  *(uint4*)(A2T + (size_t)t*1024 + lane*8)       = re.v;
  *(uint4*)(A2T + (size_t)t*1024 + 512 + lane*8) = im.v;
}

// A2[s][t] = A2T[t][s];  A2T: [512][1024], A2: [1024][512]
__global__ __launch_bounds__(256) void transpose_A(const unsigned short* __restrict__ A2T,
                                                   unsigned short* __restrict__ A2){
  __shared__ unsigned short tile[64][65];
  int tt0 = blockIdx.x * 64;   // 8 tiles over t
  int ss0 = blockIdx.y * 64;   // 16 tiles over s
  int lt = threadIdx.x & 63;
  int g  = threadIdx.x >> 6;
  #pragma unroll
  for (int r = g; r < 64; r += 4)
    tile[r][lt] = A2T[(size_t)(tt0 + r)*1024 + ss0 + lt];
  __syncthreads();
  #pragma unroll
  for (int r = g; r < 64; r += 4)
    A2[(size_t)(ss0 + r)*512 + tt0 + lt] = tile[lt][r];
}

// One wave per sample b; lane writes 8 contiguous bf16 (16B) -> coalesced.
__global__ __launch_bounds__(256) void build_c(const float* __restrict__ adds,
                                               unsigned short* __restrict__ cT, int B){
  int b = (int)((blockIdx.x * 256 + threadIdx.x) >> 6);
  int lane = threadIdx.x & 63;
  if (b >= B) return;
  const float* ab = adds + b * NQ;
  float cw[NQ], sw[NQ];
  #pragma unroll
  for (int w = 0; w < NQ; ++w)
    __sincosf(0.5f * ab[w], &sw[w], &cw[w]);
  float p6 = 1.f;
  #pragma unroll
  for (int w = 0; w < 6; ++w)
    p6 *= ((lane >> (5 - w)) & 1) ? sw[w] : cw[w];
  union { unsigned short u[8]; uint4 v; } pk;
  #pragma unroll
  for (int j = 0; j < 8; ++j){
    float p = p6 * (((j>>2)&1) ? sw[6] : cw[6])
                 * (((j>>1)&1) ? sw[7] : cw[7])
                 * (( j    &1) ? sw[8] : cw[8]);
    pk.u[j] = f2bf(p);
  }
  *(uint4*)(cT + (size_t)b * NS + lane*8) = pk.v;
}

// Phi2 = A2(1024x512) @ c(512xB); out[b] = sum_row sign(row) * Phi2[row][b]^2,
// sign(row) = -1 iff (row & 256).
__global__ __launch_bounds__(256) void gemm_out(const unsigned short* __restrict__ A2,
                                                const unsigned short* __restrict__ cT,
                                                float* __restrict__ out){
  int bx = blockIdx.x;            // N tile (128 cols of b)
  int by = blockIdx.y;            // M tile (128 rows), 8 tiles
  int tid = threadIdx.x;
  int wave = tid >> 6, lane = tid & 63;
  int wy = wave >> 1, wx = wave & 1;
  int lane15 = lane & 15, quad = lane >> 4;
  int rowBase = by*128 + wy*64;
  int colBase = bx*128 + wx*64;
  const short* Ap = (const short*)A2;   // [row][k]
  const short* Bp = (const short*)cT;   // [col][k]

  f32x4 acc[4][4];
  #pragma unroll
  for (int i = 0; i < 4; ++i)
    #pragma unroll
    for (int j = 0; j < 4; ++j)
      acc[i][j] = (f32x4){0.f, 0.f, 0.f, 0.f};

  #pragma unroll 2
  for (int k0 = 0; k0 < NS; k0 += 32){
    bf16x8 a[4], b[4];
    #pragma unroll
    for (int mi = 0; mi < 4; ++mi)
      a[mi] = *(const bf16x8*)(Ap + (size_t)(rowBase + mi*16 + lane15)*NS + k0 + quad*8);
    #pragma unroll
    for (int ni = 0; ni < 4; ++ni)
      b[ni] = *(const bf16x8*)(Bp + (size_t)(colBase + ni*16 + lane15)*NS + k0 + quad*8);
    #pragma unroll
    for (int mi = 0; mi < 4; ++mi)
      #pragma unroll
      for (int ni = 0; ni < 4; ++ni)
        acc[mi][ni] = __builtin_amdgcn_mfma_f32_16x16x32_bf16(a[mi], b[ni], acc[mi][ni], 0, 0, 0);
  }

  float sign = (by & 2) ? -1.f : 1.f;
  #pragma unroll
  for (int ni = 0; ni < 4; ++ni){
    float cs = 0.f;
    #pragma unroll
    for (int mi = 0; mi < 4; ++mi)
      #pragma unroll
      for (int r = 0; r < 4; ++r)
        cs += acc[mi][ni][r] * acc[mi][ni][r];
    cs += __shfl_xor(cs, 16);
    cs += __shfl_xor(cs, 32);
    if (quad == 0)
      atomicAdd(out + colBase + ni*16 + lane15, sign * cs);
  }
}

extern "C" void kernel_launch(void* const* d_in, const int* in_sizes, int n_in,
                              void* d_out, int out_size, void* d_ws, size_t ws_size,
                              hipStream_t stream) {
  const float* adds    = (const float*)d_in[0];
  const float* params  = (const float*)d_in[1];
  const float* weights = (const float*)d_in[2];
  const float* params2 = (const float*)d_in[3];
  float* out = (float*)d_out;
  int B = in_sizes[0] / NQ;   // 8192

  unsigned short* A2  = (unsigned short*)d_ws;       // 1024*512 bf16 = 1 MB
  unsigned short* cT  = A2 + (size_t)M2 * NS;        // B*512 bf16 = 8 MB
  unsigned short* A2T = cT;                          // alias: used before build_c runs

  hipMemsetAsync(d_out, 0, (size_t)B * sizeof(float), stream);
  hipLaunchKernelGGL(sim_V, dim3(NS), dim3(64), 0, stream, params, weights, params2, A2T);
  hipLaunchKernelGGL(transpose_A, dim3(8, 16), dim3(256), 0, stream, A2T, A2);
  hipLaunchKernelGGL(build_c, dim3((B * 64 + 255) / 256), dim3(256), 0, stream, adds, cT, B);
  hipLaunchKernelGGL(gemm_out, dim3(B / 128, 8), dim3(256), 0, stream, A2, cT, out);
}

// Round 3
// 139.445 us; speedup vs baseline: 1.6493x; 1.2500x over previous
//
#include <hip/hip_runtime.h>

#define NQ 9
#define NS 512            // 2^9 amplitudes
#define M2 1024           // [Re V; Im V] stacked rows

typedef __attribute__((ext_vector_type(8))) short bf16x8;
typedef __attribute__((ext_vector_type(4))) float f32x4;

__device__ inline unsigned short f2bf(float f){
  unsigned int u = __float_as_uint(f);
  u += 0x7fffu + ((u >> 16) & 1u);   // round-to-nearest-even
  return (unsigned short)(u >> 16);
}

// =====================  2-wave register-resident statevector sim  =====================
// One block (2 waves, 128 thr) per column t. Amp index i (9 bits):
//   bit 8   -> wave (wv)
//   bits 2-7-> lane bits 0-5  (lane mask 1<<(B-2))
//   bits 0-1-> register index j (4 complex amps per lane)
// Wire w <-> bit (8-w): wire0=wave, wires1-6=lane(lm32..lm1), wires7,8=reg(m2,m1).

template<int LM>
__device__ inline float lxor(float v){
  if constexpr (LM == 1)       // quad_perm [1,0,3,2]
    return __int_as_float(__builtin_amdgcn_mov_dpp(__float_as_int(v), 0xB1, 0xF, 0xF, true));
  else if constexpr (LM == 2)  // quad_perm [2,3,0,1]
    return __int_as_float(__builtin_amdgcn_mov_dpp(__float_as_int(v), 0x4E, 0xF, 0xF, true));
  else
    return __shfl_xor(v, LM);
}

template<int BC>
__device__ inline bool ctrlbit(int j, int lane, int wv){
  if constexpr (BC < 2)      return (j & (1 << BC)) != 0;
  else if constexpr (BC < 8) return (lane & (1 << (BC - 2))) != 0;
  else                       return wv != 0;
}

// cross-wave exchange of all 4 complex amps (partner = same lane/reg, other wave)
__device__ inline void wexch(float2 (*exb)[128], int wv, int lane,
                             const float ax[4], const float ay[4],
                             float px[4], float py[4]){
  __syncthreads();                       // partner finished reading previous contents
  #pragma unroll
  for (int j = 0; j < 4; ++j) exb[j][(wv << 6) | lane] = make_float2(ax[j], ay[j]);
  __syncthreads();
  #pragma unroll
  for (int j = 0; j < 4; ++j){
    float2 p = exb[j][((wv ^ 1) << 6) | lane];
    px[j] = p.x; py[j] = p.y;
  }
}

template<int BT>
__device__ inline void g_ry(float ax[4], float ay[4], int lane, int wv,
                            float2 (*exb)[128], float c, float s){
  if constexpr (BT == 8){
    float px[4], py[4];
    wexch(exb, wv, lane, ax, ay, px, py);
    float se = wv ? s : -s;
    #pragma unroll
    for (int j = 0; j < 4; ++j){
      ax[j] = c*ax[j] + se*px[j];
      ay[j] = c*ay[j] + se*py[j];
    }
  } else if constexpr (BT >= 2){
    constexpr int LT = 1 << (BT - 2);
    float se = (lane & LT) ? s : -s;
    #pragma unroll
    for (int j = 0; j < 4; ++j){
      float px = lxor<LT>(ax[j]), py = lxor<LT>(ay[j]);
      ax[j] = c*ax[j] + se*px;
      ay[j] = c*ay[j] + se*py;
    }
  } else {
    constexpr int mt = 1 << BT;
    #pragma unroll
    for (int j0 = 0; j0 < 4; ++j0) if (!(j0 & mt)){
      int j1 = j0 | mt;
      float x0 = ax[j0], x1 = ax[j1];
      ax[j0] = c*x0 - s*x1;  ax[j1] = s*x0 + c*x1;
      float y0 = ay[j0], y1 = ay[j1];
      ay[j0] = c*y0 - s*y1;  ay[j1] = s*y0 + c*y1;
    }
  }
}

template<int BT>
__device__ inline void g_rot(float ax[4], float ay[4], int lane, int wv, float2 (*exb)[128],
                             float u00x,float u00y,float u01x,float u01y,
                             float u10x,float u10y,float u11x,float u11y){
  if constexpr (BT == 8){
    float px[4], py[4];
    wexch(exb, wv, lane, ax, ay, px, py);
    bool hi = wv != 0;
    float cax = hi?u11x:u00x, cay = hi?u11y:u00y;
    float cbx = hi?u10x:u01x, cby = hi?u10y:u01y;
    #pragma unroll
    for (int j = 0; j < 4; ++j){
      float ox = ax[j], oy = ay[j];
      ax[j] = cax*ox - cay*oy + cbx*px[j] - cby*py[j];
      ay[j] = cax*oy + cay*ox + cbx*py[j] + cby*px[j];
    }
  } else if constexpr (BT >= 2){
    constexpr int LT = 1 << (BT - 2);
    bool hi = (lane & LT) != 0;
    float cax = hi?u11x:u00x, cay = hi?u11y:u00y;
    float cbx = hi?u10x:u01x, cby = hi?u10y:u01y;
    #pragma unroll
    for (int j = 0; j < 4; ++j){
      float px = lxor<LT>(ax[j]), py = lxor<LT>(ay[j]);
      float ox = ax[j], oy = ay[j];
      ax[j] = cax*ox - cay*oy + cbx*px - cby*py;
      ay[j] = cax*oy + cay*ox + cbx*py + cby*px;
    }
  } else {
    constexpr int mt = 1 << BT;
    #pragma unroll
    for (int j0 = 0; j0 < 4; ++j0) if (!(j0 & mt)){
      int j1 = j0 | mt;
      float x0=ax[j0], y0=ay[j0], x1=ax[j1], y1=ay[j1];
      ax[j0] = u00x*x0 - u00y*y0 + u01x*x1 - u01y*y1;
      ay[j0] = u00x*y0 + u00y*x0 + u01x*y1 + u01y*x1;
      ax[j1] = u10x*x0 - u10y*y0 + u11x*x1 - u11y*y1;
      ay[j1] = u10x*y0 + u10y*x0 + u11x*y1 + u11y*x1;
    }
  }
}

// Fused CNOT(c,t) ; CRZ(c,t,th2) ; X(t) ; CRX(c,t,th3):
//   c=0: swap target pair.
//   c=1: out_t0 = alpha*a_t0 + beta*a_t1 ; out_t1 = conj(alpha)*a_t1 - conj(beta)*a_t0
//        alpha = c3*e^{+i th2/2},  beta = -i s3 e^{-i th2/2}
// Uniform per-amp form: out(c=1) = (Ax + i*(t? -Ay:Ay))*own + ((t? -Bx:Bx) + i*By)*partner
template<int BC, int BT>
__device__ inline void g_ent2q(float ax[4], float ay[4], int lane, int wv, float2 (*exb)[128],
                               float c2, float s2, float c3, float s3){
  const float Ax = c3*c2, Ay = c3*s2, Bx = -s3*s2, By = -s3*c2;
  if constexpr (BT == 8){
    float px[4], py[4];
    wexch(exb, wv, lane, ax, ay, px, py);
    bool tb = wv != 0;
    float Ay2 = tb ? -Ay : Ay, Bx2 = tb ? -Bx : Bx;
    #pragma unroll
    for (int j = 0; j < 4; ++j){
      float ox = ax[j], oy = ay[j];
      float nx = Ax*ox - Ay2*oy + Bx2*px[j] - By*py[j];
      float ny = Ax*oy + Ay2*ox + Bx2*py[j] + By*px[j];
      bool cb = ctrlbit<BC>(j, lane, wv);
      ax[j] = cb ? nx : px[j];
      ay[j] = cb ? ny : py[j];
    }
  } else if constexpr (BT >= 2){
    constexpr int LT = 1 << (BT - 2);
    bool tb = (lane & LT) != 0;
    float Ay2 = tb ? -Ay : Ay, Bx2 = tb ? -Bx : Bx;
    #pragma unroll
    for (int j = 0; j < 4; ++j){
      float px = lxor<LT>(ax[j]), py = lxor<LT>(ay[j]);
      float ox = ax[j], oy = ay[j];
      float nx = Ax*ox - Ay2*oy + Bx2*px - By*py;
      float ny = Ax*oy + Ay2*ox + Bx2*py + By*px;
      bool cb = ctrlbit<BC>(j, lane, wv);
      ax[j] = cb ? nx : px;
      ay[j] = cb ? ny : py;
    }
  } else {
    constexpr int mt = 1 << BT;
    #pragma unroll
    for (int j0 = 0; j0 < 4; ++j0) if (!(j0 & mt)){
      int j1 = j0 | mt;
      float x0=ax[j0], y0=ay[j0], x1=ax[j1], y1=ay[j1];
      float nx0 = Ax*x0 - Ay*y0 + Bx*x1 - By*y1;
      float ny0 = Ax*y0 + Ay*x0 + Bx*y1 + By*x1;
      float nx1 = Ax*x1 + Ay*y1 - Bx*x0 - By*y0;
      float ny1 = Ax*y1 - Ay*x1 - Bx*y0 + By*x0;
      bool cb = ctrlbit<BC>(j0, lane, wv);
      ax[j0] = cb ? nx0 : x1;  ay[j0] = cb ? ny0 : y1;
      ax[j1] = cb ? nx1 : x0;  ay[j1] = cb ? ny1 : y0;
    }
  }
}

template<int BC, int BT>
__device__ inline void g_cnot(float ax[4], float ay[4], int lane, int wv, float2 (*exb)[128]){
  if constexpr (BT == 8){
    float px[4], py[4];
    wexch(exb, wv, lane, ax, ay, px, py);
    #pragma unroll
    for (int j = 0; j < 4; ++j){
      bool cb = ctrlbit<BC>(j, lane, wv);
      ax[j] = cb ? px[j] : ax[j];
      ay[j] = cb ? py[j] : ay[j];
    }
  } else if constexpr (BT >= 2){
    constexpr int LT = 1 << (BT - 2);
    #pragma unroll
    for (int j = 0; j < 4; ++j){
      float px = lxor<LT>(ax[j]), py = lxor<LT>(ay[j]);
      bool cb = ctrlbit<BC>(j, lane, wv);
      ax[j] = cb ? px : ax[j];
      ay[j] = cb ? py : ay[j];
    }
  } else {
    constexpr int mt = 1 << BT;
    #pragma unroll
    for (int j0 = 0; j0 < 4; ++j0) if (!(j0 & mt)){
      int j1 = j0 | mt;
      bool cb = ctrlbit<BC>(j0, lane, wv);
      float x0=ax[j0], y0=ay[j0], x1=ax[j1], y1=ay[j1];
      ax[j0] = cb?x1:x0; ay[j0] = cb?y1:y0;
      ax[j1] = cb?x0:x1; ay[j1] = cb?y0:y1;
    }
  }
}

// ---------------- circuit drivers ----------------

template<int I>
__device__ inline void ent_step(float ax[4], float ay[4], int lane, int wv,
                                float2 (*exb)[128], const float* __restrict__ p){
  constexpr int IP = (I + 1) % 9;
  float s0,c0,s1,c1,s2,c2,s3,c3;
  __sincosf(0.5f*p[4*I+0], &s0, &c0);
  __sincosf(0.5f*p[4*I+1], &s1, &c1);
  __sincosf(0.5f*p[4*I+2], &s2, &c2);
  __sincosf(0.5f*p[4*I+3], &s3, &c3);
  g_ry<8-I >(ax, ay, lane, wv, exb, c0, s0);
  g_ry<8-IP>(ax, ay, lane, wv, exb, c1, s1);
  g_ent2q<8-I, 8-IP>(ax, ay, lane, wv, exb, c2, s2, c3, s3);
}

template<int I = 0>
__device__ inline void ent_block(float ax[4], float ay[4], int lane, int wv,
                                 float2 (*exb)[128], const float* __restrict__ p){
  ent_step<I>(ax, ay, lane, wv, exb, p);
  if constexpr (I < 8) ent_block<I+1>(ax, ay, lane, wv, exb, p);
}

template<int I>
__device__ inline void rot_one(float ax[4], float ay[4], int lane, int wv,
                               float2 (*exb)[128], const float* __restrict__ w){
  float phi = w[3*I], th = w[3*I+1], om = w[3*I+2];
  float sT,cT,sA,cA,sB,cB;
  __sincosf(0.5f*th, &sT, &cT);
  __sincosf(0.5f*(phi+om), &sA, &cA);
  __sincosf(0.5f*(om-phi), &sB, &cB);
  g_rot<8-I>(ax, ay, lane, wv, exb,
             cA*cT, -sA*cT,
            -cB*sT,  sB*sT,
             cB*sT,  sB*sT,
             cA*cT,  sA*cT);
}

template<int I = 0>
__device__ inline void sel_rots(float ax[4], float ay[4], int lane, int wv,
                                float2 (*exb)[128], const float* __restrict__ w){
  rot_one<I>(ax, ay, lane, wv, exb, w);
  if constexpr (I < 8) sel_rots<I+1>(ax, ay, lane, wv, exb, w);
}

template<int R, int I = 0>
__device__ inline void sel_cnots(float ax[4], float ay[4], int lane, int wv, float2 (*exb)[128]){
  g_cnot<8-I, 8-((I+R)%9)>(ax, ay, lane, wv, exb);
  if constexpr (I < 8) sel_cnots<R, I+1>(ax, ay, lane, wv, exb);
}

template<int R>
__device__ inline void sel_layer(float ax[4], float ay[4], int lane, int wv,
                                 float2 (*exb)[128], const float* __restrict__ w){
  sel_rots<0>(ax, ay, lane, wv, exb, w);
  sel_cnots<R, 0>(ax, ay, lane, wv, exb);
}

// One block (2 waves) per column t. Writes A2[s][t] directly (scattered 2B stores).
__global__ __launch_bounds__(128) void sim_V(const float* __restrict__ params,
                                             const float* __restrict__ weights,
                                             const float* __restrict__ params2,
                                             unsigned short* __restrict__ A2){
  __shared__ float2 exb[4][128];
  int t = blockIdx.x;
  int wv = threadIdx.x >> 6, lane = threadIdx.x & 63;
  float ax[4], ay[4];
  int pc = __popc((unsigned)t) & 3;
  float prx = (pc==0) ? 1.f : (pc==2 ? -1.f : 0.f);
  float pry = (pc==3) ? 1.f : (pc==1 ? -1.f : 0.f);
  int wv_t = t >> 8, ln_t = (t >> 2) & 63, j_t = t & 3;
  #pragma unroll
  for (int j = 0; j < 4; ++j){
    bool hit = (wv == wv_t) && (lane == ln_t) && (j == j_t);
    ax[j] = hit ? prx : 0.f;
    ay[j] = hit ? pry : 0.f;
  }
  ent_block<0>(ax, ay, lane, wv, exb, params);
  ent_block<0>(ax, ay, lane, wv, exb, params + 36);
  ent_block<0>(ax, ay, lane, wv, exb, params + 72);
  sel_layer<1>(ax, ay, lane, wv, exb, weights);
  sel_layer<2>(ax, ay, lane, wv, exb, weights + 27);
  sel_layer<3>(ax, ay, lane, wv, exb, weights + 54);
  ent_block<0>(ax, ay, lane, wv, exb, params2);
  ent_block<0>(ax, ay, lane, wv, exb, params2 + 36);
  ent_block<0>(ax, ay, lane, wv, exb, params2 + 72);
  ent_block<0>(ax, ay, lane, wv, exb, params2 + 108);
  ent_block<0>(ax, ay, lane, wv, exb, params2 + 144);

  int sbase = (wv << 8) | (lane << 2);
  #pragma unroll
  for (int j = 0; j < 4; ++j){
    int s = sbase + j;
    A2[(size_t)s * NS + t]        = f2bf(ax[j]);
    A2[(size_t)(s + NS) * NS + t] = f2bf(ay[j]);
  }
}

// build_c (wave per sample, coalesced 16B stores) + zero the output accumulator
__global__ __launch_bounds__(256) void prep(const float* __restrict__ adds,
                                            unsigned short* __restrict__ cT,
                                            float* __restrict__ out, int B){
  int gid = blockIdx.x * 256 + threadIdx.x;
  int b = gid >> 6;
  int lane = gid & 63;
  if (b < B){
    const float* ab = adds + b * NQ;
    float cw[NQ], sw[NQ];
    #pragma unroll
    for (int w = 0; w < NQ; ++w)
      __sincosf(0.5f * ab[w], &sw[w], &cw[w]);
    float p6 = 1.f;
    #pragma unroll
    for (int w = 0; w < 6; ++w)
      p6 *= ((lane >> (5 - w)) & 1) ? sw[w] : cw[w];
    union { unsigned short u[8]; uint4 v; } pk;
    #pragma unroll
    for (int j = 0; j < 8; ++j){
      float p = p6 * (((j>>2)&1) ? sw[6] : cw[6])
                   * (((j>>1)&1) ? sw[7] : cw[7])
                   * (( j    &1) ? sw[8] : cw[8]);
      pk.u[j] = f2bf(p);
    }
    *(uint4*)(cT + (size_t)b * NS + lane*8) = pk.v;
  }
  if (gid < B) out[gid] = 0.f;
}

// Phi2 = A2(1024x512) @ c(512xB); out[b] = sum_row sign(row) * Phi2[row][b]^2,
// sign(row) = -1 iff (row & 256).
__global__ __launch_bounds__(256) void gemm_out(const unsigned short* __restrict__ A2,
                                                const unsigned short* __restrict__ cT,
                                                float* __restrict__ out){
  int bx = blockIdx.x;            // N tile (128 cols of b)
  int by = blockIdx.y;            // M tile (128 rows), 8 tiles
  int tid = threadIdx.x;
  int wave = tid >> 6, lane = tid & 63;
  int wy = wave >> 1, wx = wave & 1;
  int lane15 = lane & 15, quad = lane >> 4;
  int rowBase = by*128 + wy*64;
  int colBase = bx*128 + wx*64;
  const short* Ap = (const short*)A2;   // [row][k]
  const short* Bp = (const short*)cT;   // [col][k]

  f32x4 acc[4][4];
  #pragma unroll
  for (int i = 0; i < 4; ++i)
    #pragma unroll
    for (int j = 0; j < 4; ++j)
      acc[i][j] = (f32x4){0.f, 0.f, 0.f, 0.f};

  #pragma unroll 2
  for (int k0 = 0; k0 < NS; k0 += 32){
    bf16x8 a[4], b[4];
    #pragma unroll
    for (int mi = 0; mi < 4; ++mi)
      a[mi] = *(const bf16x8*)(Ap + (size_t)(rowBase + mi*16 + lane15)*NS + k0 + quad*8);
    #pragma unroll
    for (int ni = 0; ni < 4; ++ni)
      b[ni] = *(const bf16x8*)(Bp + (size_t)(colBase + ni*16 + lane15)*NS + k0 + quad*8);
    #pragma unroll
    for (int mi = 0; mi < 4; ++mi)
      #pragma unroll
      for (int ni = 0; ni < 4; ++ni)
        acc[mi][ni] = __builtin_amdgcn_mfma_f32_16x16x32_bf16(a[mi], b[ni], acc[mi][ni], 0, 0, 0);
  }

  float sign = (by & 2) ? -1.f : 1.f;
  #pragma unroll
  for (int ni = 0; ni < 4; ++ni){
    float cs = 0.f;
    #pragma unroll
    for (int mi = 0; mi < 4; ++mi)
      #pragma unroll
      for (int r = 0; r < 4; ++r)
        cs += acc[mi][ni][r] * acc[mi][ni][r];
    cs += __shfl_xor(cs, 16);
    cs += __shfl_xor(cs, 32);
    if (quad == 0)
      atomicAdd(out + colBase + ni*16 + lane15, sign * cs);
  }
}

extern "C" void kernel_launch(void* const* d_in, const int* in_sizes, int n_in,
                              void* d_out, int out_size, void* d_ws, size_t ws_size,
                              hipStream_t stream) {
  const float* adds    = (const float*)d_in[0];
  const float* params  = (const float*)d_in[1];
  const float* weights = (const float*)d_in[2];
  const float* params2 = (const float*)d_in[3];
  float* out = (float*)d_out;
  int B = in_sizes[0] / NQ;   // 8192

  unsigned short* A2 = (unsigned short*)d_ws;        // 1024*512 bf16 = 1 MB
  unsigned short* cT = A2 + (size_t)M2 * NS;         // B*512 bf16 = 8 MB

  hipLaunchKernelGGL(sim_V, dim3(NS), dim3(128), 0, stream, params, weights, params2, A2);
  hipLaunchKernelGGL(prep, dim3((B * 64 + 255) / 256), dim3(256), 0, stream, adds, cT, out, B);
  hipLaunchKernelGGL(gemm_out, dim3(B / 128, 8), dim3(256), 0, stream, A2, cT, out);
}